// Round 5
// baseline (655.035 us; speedup 1.0000x reference)
//
#include <hip/hip_runtime.h>
#include <hip/hip_bf16.h>
#include <hip/hip_fp16.h>
#include <math.h>

// Problem constants
#define B_   256
#define HID_ 1024
#define SP_  2048
#define N_   196        // 14*14
#define NJ_  (B_ * N_)  // 50176 = 392 * 128
#define SPB_ (SP_ * N_) // elems per batch of spatial

typedef float    f32x4 __attribute__((ext_vector_type(4)));
typedef _Float16 f16x8 __attribute__((ext_vector_type(8)));

#define GLOBAL_AS(p) ((const __attribute__((address_space(1))) void*)(p))
#define LDS_AS(p)    ((__attribute__((address_space(3))) void*)(p))

// ---------------------------------------------------------------------------
// K1: h1[b,d] = hidden @ W1h + b1   (256x1024 @ 1024x1024)
// ---------------------------------------------------------------------------
__global__ __launch_bounds__(256) void k1_h1(
    const float* __restrict__ hidden, const float* __restrict__ W1,
    const float* __restrict__ b1, float* __restrict__ h1)
{
    __shared__ float hs[8][HID_];
    const int t = threadIdx.x;
    const int d = blockIdx.x * 256 + t;
    const int b0 = blockIdx.y * 8;

    for (int i = t; i < 8 * HID_; i += 256)
        hs[i >> 10][i & 1023] = hidden[(size_t)(b0 + (i >> 10)) * HID_ + (i & 1023)];
    __syncthreads();

    float acc[8] = {};
    for (int h = 0; h < HID_; ++h) {
        const float w = W1[(size_t)h * HID_ + d];
#pragma unroll
        for (int i = 0; i < 8; ++i) acc[i] += hs[i][h] * w;
    }
    const float bias = b1[d];
#pragma unroll
    for (int i = 0; i < 8; ++i)
        h1[(size_t)(b0 + i) * HID_ + d] = acc[i] + bias;
}

// ---------------------------------------------------------------------------
// K0a: pack A = W1s^T (d x c, 1024x2048) into fp16 tiles.
// Tile (dt, cs): 128 d x 32 c, layout [cg(4)][dd(128)][c8(8)], 4096 elems.
// ---------------------------------------------------------------------------
__global__ __launch_bounds__(256) void k0a_packA(
    const float* __restrict__ W1, __half* __restrict__ Ah)
{
    const size_t idx = (size_t)blockIdx.x * 256 + threadIdx.x;  // < 2,097,152
    const int dt = idx >> 18;
    const int cs = (idx >> 12) & 63;
    const int e  = idx & 4095;
    const int cg = e >> 10, dd = (e >> 3) & 127, c8 = e & 7;
    const int d = dt * 128 + dd;
    const int c = cs * 32 + cg * 8 + c8;
    Ah[idx] = __float2half(W1[(size_t)(HID_ + c) * HID_ + d]);
}

// ---------------------------------------------------------------------------
// K2 (MFMA): C[d,j] = A·B single-pass fp16; B reg-staged from fp32 spatial.
// 2-phase double-buffered pipeline (T3 minimum) + T14 issue-early/write-late:
//   phase: { issue B(t+1)->regs, issue A(t+1)->gload_lds | ds_read+MFMA(t) |
//            cvt+ds_write B(t+1) | barrier }
// 128x128 tile, BK=32, 4 waves (2d x 2j), 16x16x32 MFMA f16, 4x4 frags/wave.
// ---------------------------------------------------------------------------
__global__ __launch_bounds__(256, 2) void k2_mfma(
    const __half* __restrict__ Ah, const float* __restrict__ spatial,
    const float* __restrict__ W2, const float* __restrict__ h1,
    float* __restrict__ ps)
{
    __shared__ __align__(16) short lds[4][4096];  // A0,B0,A1,B1 (8 KB each)

    const int tid = threadIdx.x;
    const int l = tid & 63;
    const int w = tid >> 6;           // wave 0..3
    const int wd = w >> 1, wj = w & 1;
    const int cg = l >> 4, r = l & 15;

    // XCD-chunked swizzle: dt fastest -> jt's spatial panel reused 8x in L2.
    const int f = blockIdx.x;
    const int xcd = f & 7, p = f >> 3;
    const int dt = p & 7;               // 0..7
    const int jt = xcd * 49 + (p >> 3); // 0..391

    // B staging mapping: thread owns column jj, half the c's.
    const int jj = tid & 127;
    const int chalf = tid >> 7;         // c = cs*32 + chalf*16 + k
    const int jg0 = jt * 128 + jj;
    const int bb0 = jg0 / N_;
    const int nn0 = jg0 - bb0 * N_;
    const float* bsrc = spatial + (size_t)bb0 * SPB_ + nn0 + (size_t)(chalf * 16) * N_;
    const int bwoff0 = ((chalf * 2 + 0) * 128 + jj) * 8;
    const int bwoff1 = ((chalf * 2 + 1) * 128 + jj) * 8;
    const __half* abase = Ah + ((size_t)dt * 64) * 4096;

    f32x4 acc[4][4] = {};
    float bv[16];

#define B_LOAD(CS) do {                                                        \
        const float* bs_ = bsrc + (size_t)(CS) * 32 * N_;                      \
        _Pragma("unroll")                                                      \
        for (int k_ = 0; k_ < 16; ++k_) bv[k_] = bs_[(size_t)k_ * N_];         \
    } while (0)

#define A_ISSUE(CS, ABUF) do {                                                 \
        const __half* as_ = abase + (size_t)(CS) * 4096;                       \
        __builtin_amdgcn_global_load_lds(GLOBAL_AS(as_ + (size_t)(w * 64 + l) * 8), \
            LDS_AS(&lds[ABUF][(w * 64) * 8]), 16, 0, 0);                       \
        __builtin_amdgcn_global_load_lds(GLOBAL_AS(as_ + (size_t)(256 + w * 64 + l) * 8), \
            LDS_AS(&lds[ABUF][(256 + w * 64) * 8]), 16, 0, 0);                 \
    } while (0)

#define B_WRITE(BBUF) do {                                                     \
        f16x8 h0_, h1_;                                                        \
        _Pragma("unroll")                                                      \
        for (int k_ = 0; k_ < 8; ++k_) {                                       \
            h0_[k_] = (_Float16)bv[k_];                                        \
            h1_[k_] = (_Float16)bv[k_ + 8];                                    \
        }                                                                      \
        *(f16x8*)&lds[BBUF][bwoff0] = h0_;                                     \
        *(f16x8*)&lds[BBUF][bwoff1] = h1_;                                     \
    } while (0)

#define COMPUTE(ABUF, BBUF) do {                                               \
        f16x8 a_h[4], b_h[4];                                                  \
        _Pragma("unroll")                                                      \
        for (int mi = 0; mi < 4; ++mi) {                                       \
            const int dd_ = wd * 64 + mi * 16 + r;                             \
            a_h[mi] = *(const f16x8*)&lds[ABUF][(cg * 128 + dd_) * 8];         \
        }                                                                      \
        _Pragma("unroll")                                                      \
        for (int ni = 0; ni < 4; ++ni) {                                       \
            const int jf_ = wj * 64 + ni * 16 + r;                             \
            b_h[ni] = *(const f16x8*)&lds[BBUF][(cg * 128 + jf_) * 8];         \
        }                                                                      \
        _Pragma("unroll")                                                      \
        for (int mi = 0; mi < 4; ++mi)                                         \
            _Pragma("unroll")                                                  \
            for (int ni = 0; ni < 4; ++ni)                                     \
                acc[mi][ni] = __builtin_amdgcn_mfma_f32_16x16x32_f16(          \
                    a_h[mi], b_h[ni], acc[mi][ni], 0, 0, 0);                   \
    } while (0)

    // prologue: stage cs=0 into buffers 0(A),1(B)
    B_LOAD(0);
    A_ISSUE(0, 0);
    B_WRITE(1);
    __syncthreads();

    for (int cs = 0; cs < 64; cs += 2) {
        // phase 0: compute (0,1), stage cs+1 -> (2,3)
        B_LOAD(cs + 1);
        A_ISSUE(cs + 1, 2);
        COMPUTE(0, 1);
        B_WRITE(3);
        __syncthreads();

        // phase 1: compute (2,3), stage cs+2 -> (0,1)
        const bool more = (cs + 2) < 64;
        if (more) {
            B_LOAD(cs + 2);
            A_ISSUE(cs + 2, 0);
        }
        COMPUTE(2, 3);
        if (more) B_WRITE(1);
        __syncthreads();
    }

    // Epilogue: partial[j] = sum_d tanh(acc + h1) * w2
    const int q4 = cg * 4;
    float w2v[4][4];
#pragma unroll
    for (int mi = 0; mi < 4; ++mi)
#pragma unroll
        for (int q = 0; q < 4; ++q)
            w2v[mi][q] = W2[dt * 128 + wd * 64 + mi * 16 + q4 + q];

    float partial[4];
#pragma unroll
    for (int ni = 0; ni < 4; ++ni) {
        const int jge = jt * 128 + wj * 64 + ni * 16 + r;
        const int bj = jge / N_;
        const float* h1p = h1 + (size_t)bj * HID_ + dt * 128 + wd * 64;
        float s = 0.f;
#pragma unroll
        for (int mi = 0; mi < 4; ++mi)
#pragma unroll
            for (int q = 0; q < 4; ++q)
                s += tanhf(acc[mi][ni][q] + h1p[mi * 16 + q4 + q]) * w2v[mi][q];
        partial[ni] = s;
    }

    float* red = (float*)&lds[0][0];
    if (tid < 128) red[tid] = 0.f;
    __syncthreads();
#pragma unroll
    for (int ni = 0; ni < 4; ++ni)
        atomicAdd(&red[wj * 64 + ni * 16 + r], partial[ni]);
    __syncthreads();
    if (tid < 128)
        ps[(size_t)dt * NJ_ + (size_t)jt * 128 + tid] = red[tid];
}

// ---------------------------------------------------------------------------
// K2 fallback (fp32 vector path) if workspace is too small for packing.
// ---------------------------------------------------------------------------
__global__ __launch_bounds__(256) void k2_fb(
    const float* __restrict__ spatial, const float* __restrict__ W1,
    const float* __restrict__ W2, const float* __restrict__ h1,
    float* __restrict__ ps)
{
    __shared__ float As[32][64];
    __shared__ float Bs[32][64];
    const int t = threadIdx.x;
    const int d0 = blockIdx.x * 64;
    const int j0 = blockIdx.y * 64;
    const int ld = t & 63, lk = t >> 6;
    const float* Aptr = W1 + (size_t)(HID_ + lk) * HID_ + (d0 + ld);
    const int j = j0 + ld;
    const int bb = j / N_, nn = j - bb * N_;
    const float* Bptr = spatial + (size_t)bb * SPB_ + (size_t)lk * N_ + nn;
    const int tr = t >> 4, tc = t & 15;
    float acc[4][4] = {};
    for (int c0 = 0; c0 < SP_; c0 += 32) {
#pragma unroll
        for (int i = 0; i < 8; ++i) {
            As[lk + 4 * i][ld] = Aptr[(size_t)(c0 + 4 * i) * HID_];
            Bs[lk + 4 * i][ld] = Bptr[(size_t)(c0 + 4 * i) * N_];
        }
        __syncthreads();
#pragma unroll
        for (int k = 0; k < 32; ++k) {
            float av[4], bv[4];
            *(float4*)av = *(const float4*)&As[k][tr * 4];
            *(float4*)bv = *(const float4*)&Bs[k][tc * 4];
#pragma unroll
            for (int di = 0; di < 4; ++di)
#pragma unroll
                for (int ji = 0; ji < 4; ++ji)
                    acc[di][ji] += av[di] * bv[ji];
        }
        __syncthreads();
    }
    float w2v[4];
#pragma unroll
    for (int di = 0; di < 4; ++di) w2v[di] = W2[d0 + tr * 4 + di];
    float partial[4] = {};
#pragma unroll
    for (int ji = 0; ji < 4; ++ji) {
        const int jg = j0 + tc * 4 + ji;
        const int bj = jg / N_;
        const float* h1row = h1 + (size_t)bj * HID_ + d0 + tr * 4;
#pragma unroll
        for (int di = 0; di < 4; ++di)
            partial[ji] += tanhf(acc[di][ji] + h1row[di]) * w2v[di];
    }
    __shared__ float red[64];
    if (t < 64) red[t] = 0.f;
    __syncthreads();
#pragma unroll
    for (int ji = 0; ji < 4; ++ji)
        atomicAdd(&red[tc * 4 + ji], partial[ji]);
    __syncthreads();
    if (t < 64)
        ps[(size_t)blockIdx.x * NJ_ + j0 + t] = red[t];
}

// ---------------------------------------------------------------------------
// K3: scores[b,n] = sum_slices ps; attn = softmax_n  (b2 shift-invariant)
// ---------------------------------------------------------------------------
__global__ __launch_bounds__(256) void k3_softmax(
    const float* __restrict__ ps, float* __restrict__ attn, int nslices)
{
    const int b = blockIdx.x;
    const int t = threadIdx.x;
    __shared__ float sdata[256];

    float s = -1e30f;
    if (t < N_) {
        s = 0.f;
        for (int dt = 0; dt < nslices; ++dt)
            s += ps[(size_t)dt * NJ_ + b * N_ + t];
    }
    sdata[t] = s;
    __syncthreads();
    for (int off = 128; off > 0; off >>= 1) {
        if (t < off) sdata[t] = fmaxf(sdata[t], sdata[t + off]);
        __syncthreads();
    }
    const float m = sdata[0];
    __syncthreads();
    const float e = (t < N_) ? expf(s - m) : 0.f;
    sdata[t] = e;
    __syncthreads();
    for (int off = 128; off > 0; off >>= 1) {
        if (t < off) sdata[t] += sdata[t + off];
        __syncthreads();
    }
    const float inv = 1.f / sdata[0];
    if (t < N_) attn[(size_t)b * N_ + t] = e * inv;
}

// ---------------------------------------------------------------------------
// K4: context[b,c] = sum_n attn[b,n] * spatial[b, c*196 + n]
// 196 = 49 float4 (row base 784 B, 16B-aligned). One wave per (b,c).
// ---------------------------------------------------------------------------
__global__ __launch_bounds__(256) void k4_context(
    const float* __restrict__ spatial, const float* __restrict__ attn,
    float* __restrict__ ctx)
{
    const int wid = (blockIdx.x * 256 + threadIdx.x) >> 6;
    const int lane = threadIdx.x & 63;
    const int b = wid >> 11;
    const int c = wid & 2047;
    const float* sp = spatial + (size_t)b * SPB_ + (size_t)c * N_;
    const float* at = attn + (size_t)b * N_;

    float sum = 0.f;
    if (lane < 49) {
        const float4 s4 = ((const float4*)sp)[lane];
        const float4 a4 = ((const float4*)at)[lane];
        sum = s4.x * a4.x + s4.y * a4.y + s4.z * a4.z + s4.w * a4.w;
    }
#pragma unroll
    for (int off = 32; off > 0; off >>= 1)
        sum += __shfl_down(sum, off, 64);
    if (lane == 0)
        ctx[(size_t)b * 2048 + c] = sum;
}

// ---------------------------------------------------------------------------
extern "C" void kernel_launch(void* const* d_in, const int* in_sizes, int n_in,
                              void* d_out, int out_size, void* d_ws, size_t ws_size,
                              hipStream_t stream)
{
    const float* hidden  = (const float*)d_in[0];
    const float* spatial = (const float*)d_in[1];
    const float* W1      = (const float*)d_in[2];
    const float* b1      = (const float*)d_in[3];
    const float* W2      = (const float*)d_in[4];
    // b2 unused: softmax shift-invariant.

    float* out_ctx  = (float*)d_out;
    float* out_attn = (float*)d_out + (size_t)B_ * 2048;

    char* ws = (char*)d_ws;
    float* h1 = (float*)ws;                               // 1 MB
    float* psb = (float*)(ws + (1u << 20));               // up to 16 slices (3.2 MB)

    // MFMA-path workspace layout (A pack only, ~4 MB)
    const size_t offAh  = 8u << 20;
    const size_t needed = offAh + ((size_t)8 * 64 * 4096 * 2);  // ~12 MB

    k1_h1<<<dim3(4, 32), 256, 0, stream>>>(hidden, W1, b1, h1);

    if (ws_size >= needed) {
        __half* Ah = (__half*)(ws + offAh);
        k0a_packA<<<dim3(8192), 256, 0, stream>>>(W1, Ah);
        k2_mfma<<<dim3(3136), 256, 0, stream>>>(Ah, spatial, W2, h1, psb);
        k3_softmax<<<dim3(B_), 256, 0, stream>>>(psb, out_attn, 8);
    } else {
        k2_fb<<<dim3(16, 784), 256, 0, stream>>>(spatial, W1, W2, h1, psb);
        k3_softmax<<<dim3(B_), 256, 0, stream>>>(psb, out_attn, 16);
    }
    k4_context<<<dim3((B_ * 2048) / 4), 256, 0, stream>>>(spatial, out_attn, out_ctx);
}

// Round 6
// 544.292 us; speedup vs baseline: 1.2035x; 1.2035x over previous
//
#include <hip/hip_runtime.h>
#include <hip/hip_bf16.h>
#include <hip/hip_fp16.h>
#include <math.h>

// Problem constants
#define B_   256
#define HID_ 1024
#define SP_  2048
#define N_   196        // 14*14
#define NJ_  (B_ * N_)  // 50176 = 392 * 128
#define SPB_ (SP_ * N_) // elems per batch of spatial

typedef float    f32x4 __attribute__((ext_vector_type(4)));
typedef _Float16 f16x8 __attribute__((ext_vector_type(8)));

#define GLOBAL_AS(p) ((const __attribute__((address_space(1))) void*)(p))
#define LDS_AS(p)    ((__attribute__((address_space(3))) void*)(p))

__device__ __forceinline__ float fast_tanh(float x) {
    // tanh(x) = 1 - 2/(e^{2x}+1); exp2 is single v_exp_f32
    const float e = exp2f(x * 2.8853900817779268f);  // 2*log2(e)
    return 1.f - 2.f / (e + 1.f);
}

// ---------------------------------------------------------------------------
// K1: h1[b,d] = hidden @ W1h + b1   (256x1024 @ 1024x1024)
// 256 blocks: 4 d-tiles x 64 b-groups of 4.
// ---------------------------------------------------------------------------
__global__ __launch_bounds__(256) void k1_h1(
    const float* __restrict__ hidden, const float* __restrict__ W1,
    const float* __restrict__ b1, float* __restrict__ h1)
{
    __shared__ float hs[4][HID_];
    const int t = threadIdx.x;
    const int d = blockIdx.x * 256 + t;
    const int b0 = blockIdx.y * 4;

    for (int i = t; i < 4 * HID_; i += 256)
        hs[i >> 10][i & 1023] = hidden[(size_t)(b0 + (i >> 10)) * HID_ + (i & 1023)];
    __syncthreads();

    float acc[4] = {};
    for (int h = 0; h < HID_; ++h) {
        const float w = W1[(size_t)h * HID_ + d];
#pragma unroll
        for (int i = 0; i < 4; ++i) acc[i] += hs[i][h] * w;
    }
    const float bias = b1[d];
#pragma unroll
    for (int i = 0; i < 4; ++i)
        h1[(size_t)(b0 + i) * HID_ + d] = acc[i] + bias;
}

// ---------------------------------------------------------------------------
// K0a: pack A = W1s^T (d x c, 1024x2048) into fp16 tiles.
// Tile (dt, cs): 128 d x 32 c, layout [cg(4)][dd(128)][c8(8)], 4096 elems.
// ---------------------------------------------------------------------------
__global__ __launch_bounds__(256) void k0a_packA(
    const float* __restrict__ W1, __half* __restrict__ Ah)
{
    const size_t idx = (size_t)blockIdx.x * 256 + threadIdx.x;  // < 2,097,152
    const int dt = idx >> 18;
    const int cs = (idx >> 12) & 63;
    const int e  = idx & 4095;
    const int cg = e >> 10, dd = (e >> 3) & 127, c8 = e & 7;
    const int d = dt * 128 + dd;
    const int c = cs * 32 + cg * 8 + c8;
    Ah[idx] = __float2half(W1[(size_t)(HID_ + c) * HID_ + d]);
}

// ---------------------------------------------------------------------------
// K0b: pack B = spT (c x j) into fp16 tiles — LDS-free.
// One block per tile (jt,cs); each thread does 2 (cg,jj) positions:
// 8 c-strided reads (per-wave coalesced along j), one f16x8 store each.
// ---------------------------------------------------------------------------
__global__ __launch_bounds__(256) void k0b_packB(
    const float* __restrict__ spatial, __half* __restrict__ Bh)
{
    const int blk = blockIdx.x;            // 0..25087
    const int jt = blk >> 6;               // 0..391
    const int cs = blk & 63;               // 0..63
    const int tid = threadIdx.x;

    const int jj = tid & 127;
    const int j  = jt * 128 + jj;
    const int b  = j / N_;
    const int n  = j - b * N_;
    const float* spj = spatial + (size_t)b * SPB_ + n;
    __half* outb = Bh + ((size_t)(jt * 64 + cs)) * 4096 + jj * 8;

#pragma unroll
    for (int pz = 0; pz < 2; ++pz) {
        const int cg = (tid >> 7) + pz * 2;           // 0..3
        const float* src = spj + (size_t)(cs * 32 + cg * 8) * N_;
        f16x8 v;
#pragma unroll
        for (int c8 = 0; c8 < 8; ++c8)
            v[c8] = (_Float16)src[(size_t)c8 * N_];
        *(f16x8*)(outb + (size_t)cg * 1024) = v;
    }
}

// ---------------------------------------------------------------------------
// K2 (MFMA): C[d,j] = A·B fp16, both operands pre-packed; pure gload_lds
// staging, double-buffered, ONE barrier per K-step (stage t+1 issued before
// compute t; barrier's vmcnt drain is covered by 16 MFMA + 8 ds_read_b128).
// 128x128 tile, BK=32, 4 waves (2d x 2j), 16x16x32 MFMA f16, 4x4 frags/wave.
// Fused epilogue: partial_score[dt,j] = sum_d tanh(C + h1[bj,d]) * w2[d].
// ---------------------------------------------------------------------------
__global__ __launch_bounds__(256, 4) void k2_mfma(
    const __half* __restrict__ Ah, const __half* __restrict__ Bh,
    const float* __restrict__ W2, const float* __restrict__ h1,
    float* __restrict__ ps)
{
    __shared__ __align__(16) short lds[2][2][4096];  // [buf][A/B][tile] 32 KB

    const int tid = threadIdx.x;
    const int l = tid & 63;
    const int w = tid >> 6;           // wave 0..3
    const int wd = w >> 1, wj = w & 1;
    const int cg = l >> 4, r = l & 15;

    // XCD-chunked swizzle: dt fastest -> jt's B panel reused 8x in L2.
    const int f = blockIdx.x;
    const int xcd = f & 7, p = f >> 3;
    const int dt = p & 7;               // 0..7
    const int jt = xcd * 49 + (p >> 3); // 0..391

    const __half* abase = Ah + ((size_t)dt * 64) * 4096;
    const __half* bbase = Bh + ((size_t)jt * 64) * 4096;

    f32x4 acc[4][4] = {};

#define STAGE(BUF, CS) do {                                                     \
        const __half* as_ = abase + (size_t)(CS) * 4096;                        \
        const __half* bs_ = bbase + (size_t)(CS) * 4096;                        \
        _Pragma("unroll")                                                       \
        for (int i_ = 0; i_ < 2; ++i_) {                                        \
            __builtin_amdgcn_global_load_lds(                                   \
                GLOBAL_AS(as_ + (size_t)(i_ * 256 + w * 64 + l) * 8),           \
                LDS_AS(&lds[BUF][0][(i_ * 256 + w * 64) * 8]), 16, 0, 0);       \
            __builtin_amdgcn_global_load_lds(                                   \
                GLOBAL_AS(bs_ + (size_t)(i_ * 256 + w * 64 + l) * 8),           \
                LDS_AS(&lds[BUF][1][(i_ * 256 + w * 64) * 8]), 16, 0, 0);       \
        }                                                                       \
    } while (0)

#define COMPUTE(BUF) do {                                                       \
        f16x8 a_h[4], b_h[4];                                                   \
        _Pragma("unroll")                                                       \
        for (int mi = 0; mi < 4; ++mi) {                                        \
            const int dd_ = wd * 64 + mi * 16 + r;                              \
            a_h[mi] = *(const f16x8*)&lds[BUF][0][(cg * 128 + dd_) * 8];        \
        }                                                                       \
        _Pragma("unroll")                                                       \
        for (int ni = 0; ni < 4; ++ni) {                                        \
            const int jf_ = wj * 64 + ni * 16 + r;                              \
            b_h[ni] = *(const f16x8*)&lds[BUF][1][(cg * 128 + jf_) * 8];        \
        }                                                                       \
        _Pragma("unroll")                                                       \
        for (int mi = 0; mi < 4; ++mi)                                          \
            _Pragma("unroll")                                                   \
            for (int ni = 0; ni < 4; ++ni)                                      \
                acc[mi][ni] = __builtin_amdgcn_mfma_f32_16x16x32_f16(           \
                    a_h[mi], b_h[ni], acc[mi][ni], 0, 0, 0);                    \
    } while (0)

    STAGE(0, 0);
    __syncthreads();

    for (int cs = 0; cs < 64; ++cs) {
        if (cs + 1 < 64) STAGE((cs + 1) & 1, cs + 1);
        COMPUTE(cs & 1);
        __syncthreads();
    }
#undef STAGE
#undef COMPUTE

    // Epilogue: partial[j] = sum_d tanh(acc + h1) * w2
    const int q4 = cg * 4;
    float w2v[4][4];
#pragma unroll
    for (int mi = 0; mi < 4; ++mi)
#pragma unroll
        for (int q = 0; q < 4; ++q)
            w2v[mi][q] = W2[dt * 128 + wd * 64 + mi * 16 + q4 + q];

    float partial[4];
#pragma unroll
    for (int ni = 0; ni < 4; ++ni) {
        const int jge = jt * 128 + wj * 64 + ni * 16 + r;
        const int bj = jge / N_;
        const float* h1p = h1 + (size_t)bj * HID_ + dt * 128 + wd * 64;
        float s = 0.f;
#pragma unroll
        for (int mi = 0; mi < 4; ++mi)
#pragma unroll
            for (int q = 0; q < 4; ++q)
                s += fast_tanh(acc[mi][ni][q] + h1p[mi * 16 + q4 + q]) * w2v[mi][q];
        partial[ni] = s;
    }

    float* red = (float*)&lds[0][0][0];
    if (tid < 128) red[tid] = 0.f;
    __syncthreads();
#pragma unroll
    for (int ni = 0; ni < 4; ++ni)
        atomicAdd(&red[wj * 64 + ni * 16 + r], partial[ni]);
    __syncthreads();
    if (tid < 128)
        ps[(size_t)dt * NJ_ + (size_t)jt * 128 + tid] = red[tid];
}

// ---------------------------------------------------------------------------
// K2 fallback (fp32 vector path) if workspace is too small for packing.
// ---------------------------------------------------------------------------
__global__ __launch_bounds__(256) void k2_fb(
    const float* __restrict__ spatial, const float* __restrict__ W1,
    const float* __restrict__ W2, const float* __restrict__ h1,
    float* __restrict__ ps)
{
    __shared__ float As[32][64];
    __shared__ float Bs[32][64];
    const int t = threadIdx.x;
    const int d0 = blockIdx.x * 64;
    const int j0 = blockIdx.y * 64;
    const int ld = t & 63, lk = t >> 6;
    const float* Aptr = W1 + (size_t)(HID_ + lk) * HID_ + (d0 + ld);
    const int j = j0 + ld;
    const int bb = j / N_, nn = j - bb * N_;
    const float* Bptr = spatial + (size_t)bb * SPB_ + (size_t)lk * N_ + nn;
    const int tr = t >> 4, tc = t & 15;
    float acc[4][4] = {};
    for (int c0 = 0; c0 < SP_; c0 += 32) {
#pragma unroll
        for (int i = 0; i < 8; ++i) {
            As[lk + 4 * i][ld] = Aptr[(size_t)(c0 + 4 * i) * HID_];
            Bs[lk + 4 * i][ld] = Bptr[(size_t)(c0 + 4 * i) * N_];
        }
        __syncthreads();
#pragma unroll
        for (int k = 0; k < 32; ++k) {
            float av[4], bv[4];
            *(float4*)av = *(const float4*)&As[k][tr * 4];
            *(float4*)bv = *(const float4*)&Bs[k][tc * 4];
#pragma unroll
            for (int di = 0; di < 4; ++di)
#pragma unroll
                for (int ji = 0; ji < 4; ++ji)
                    acc[di][ji] += av[di] * bv[ji];
        }
        __syncthreads();
    }
    float w2v[4];
#pragma unroll
    for (int di = 0; di < 4; ++di) w2v[di] = W2[d0 + tr * 4 + di];
    float partial[4] = {};
#pragma unroll
    for (int ji = 0; ji < 4; ++ji) {
        const int jg = j0 + tc * 4 + ji;
        const int bj = jg / N_;
        const float* h1row = h1 + (size_t)bj * HID_ + d0 + tr * 4;
#pragma unroll
        for (int di = 0; di < 4; ++di)
            partial[ji] += tanhf(acc[di][ji] + h1row[di]) * w2v[di];
    }
    __shared__ float red[64];
    if (t < 64) red[t] = 0.f;
    __syncthreads();
#pragma unroll
    for (int ji = 0; ji < 4; ++ji)
        atomicAdd(&red[tc * 4 + ji], partial[ji]);
    __syncthreads();
    if (t < 64)
        ps[(size_t)blockIdx.x * NJ_ + j0 + t] = red[t];
}

// ---------------------------------------------------------------------------
// K3: scores[b,n] = sum_slices ps; attn = softmax_n  (b2 shift-invariant)
// ---------------------------------------------------------------------------
__global__ __launch_bounds__(256) void k3_softmax(
    const float* __restrict__ ps, float* __restrict__ attn, int nslices)
{
    const int b = blockIdx.x;
    const int t = threadIdx.x;
    __shared__ float sdata[256];

    float s = -1e30f;
    if (t < N_) {
        s = 0.f;
        for (int dt = 0; dt < nslices; ++dt)
            s += ps[(size_t)dt * NJ_ + b * N_ + t];
    }
    sdata[t] = s;
    __syncthreads();
    for (int off = 128; off > 0; off >>= 1) {
        if (t < off) sdata[t] = fmaxf(sdata[t], sdata[t + off]);
        __syncthreads();
    }
    const float m = sdata[0];
    __syncthreads();
    const float e = (t < N_) ? expf(s - m) : 0.f;
    sdata[t] = e;
    __syncthreads();
    for (int off = 128; off > 0; off >>= 1) {
        if (t < off) sdata[t] += sdata[t + off];
        __syncthreads();
    }
    const float inv = 1.f / sdata[0];
    if (t < N_) attn[(size_t)b * N_ + t] = e * inv;
}

// ---------------------------------------------------------------------------
// K4: context[b,c] = sum_n attn[b,n] * spatial[b, c*196 + n]
// 196 = 49 float4 (row base 784 B, 16B-aligned). One wave per (b,c).
// ---------------------------------------------------------------------------
__global__ __launch_bounds__(256) void k4_context(
    const float* __restrict__ spatial, const float* __restrict__ attn,
    float* __restrict__ ctx)
{
    const int wid = (blockIdx.x * 256 + threadIdx.x) >> 6;
    const int lane = threadIdx.x & 63;
    const int b = wid >> 11;
    const int c = wid & 2047;
    const float* sp = spatial + (size_t)b * SPB_ + (size_t)c * N_;
    const float* at = attn + (size_t)b * N_;

    float sum = 0.f;
    if (lane < 49) {
        const float4 s4 = ((const float4*)sp)[lane];
        const float4 a4 = ((const float4*)at)[lane];
        sum = s4.x * a4.x + s4.y * a4.y + s4.z * a4.z + s4.w * a4.w;
    }
#pragma unroll
    for (int off = 32; off > 0; off >>= 1)
        sum += __shfl_down(sum, off, 64);
    if (lane == 0)
        ctx[(size_t)b * 2048 + c] = sum;
}

// ---------------------------------------------------------------------------
extern "C" void kernel_launch(void* const* d_in, const int* in_sizes, int n_in,
                              void* d_out, int out_size, void* d_ws, size_t ws_size,
                              hipStream_t stream)
{
    const float* hidden  = (const float*)d_in[0];
    const float* spatial = (const float*)d_in[1];
    const float* W1      = (const float*)d_in[2];
    const float* b1      = (const float*)d_in[3];
    const float* W2      = (const float*)d_in[4];
    // b2 unused: softmax shift-invariant.

    float* out_ctx  = (float*)d_out;
    float* out_attn = (float*)d_out + (size_t)B_ * 2048;

    char* ws = (char*)d_ws;
    float* h1 = (float*)ws;                               // 1 MB
    float* psb = (float*)(ws + (1u << 20));               // 8 slices (1.6 MB)

    // MFMA-path workspace layout
    const size_t offAh = 8u << 20;                         // 4 MB
    const size_t offBh = 16u << 20;                        // 205 MB
    const size_t szB   = (size_t)392 * 64 * 4096 * 2;      // 205,520,896 B
    const size_t needed = offBh + szB;                     // ~212 MB

    k1_h1<<<dim3(4, 64), 256, 0, stream>>>(hidden, W1, b1, h1);

    if (ws_size >= needed) {
        __half* Ah = (__half*)(ws + offAh);
        __half* Bh = (__half*)(ws + offBh);
        k0a_packA<<<dim3(8192), 256, 0, stream>>>(W1, Ah);
        k0b_packB<<<dim3(392 * 64), 256, 0, stream>>>(spatial, Bh);
        k2_mfma<<<dim3(3136), 256, 0, stream>>>(Ah, Bh, W2, h1, psb);
        k3_softmax<<<dim3(B_), 256, 0, stream>>>(psb, out_attn, 8);
    } else {
        k2_fb<<<dim3(16, 784), 256, 0, stream>>>(spatial, W1, W2, h1, psb);
        k3_softmax<<<dim3(B_), 256, 0, stream>>>(psb, out_attn, 16);
    }
    k4_context<<<dim3((B_ * 2048) / 4), 256, 0, stream>>>(spatial, out_attn, out_ctx);
}

// Round 8
// 543.059 us; speedup vs baseline: 1.2062x; 1.0023x over previous
//
#include <hip/hip_runtime.h>
#include <hip/hip_bf16.h>
#include <hip/hip_fp16.h>
#include <math.h>

// Problem constants
#define B_   256
#define HID_ 1024
#define SP_  2048
#define N_   196        // 14*14
#define NJ_  (B_ * N_)  // 50176 = 196 * 256
#define SPB_ (SP_ * N_) // elems per batch of spatial

typedef float    f32x4 __attribute__((ext_vector_type(4)));
typedef _Float16 f16x8 __attribute__((ext_vector_type(8)));

#define GLOBAL_AS(p) ((const __attribute__((address_space(1))) void*)(p))
#define LDS_AS(p)    ((__attribute__((address_space(3))) void*)(p))

__device__ __forceinline__ float fast_tanh(float x) {
    const float e = exp2f(x * 2.8853900817779268f);  // 2*log2(e)
    return 1.f - 2.f / (e + 1.f);
}

// ---------------------------------------------------------------------------
// K1: h1[b,d] = hidden @ W1h + b1   (256x1024 @ 1024x1024)
// ---------------------------------------------------------------------------
__global__ __launch_bounds__(256) void k1_h1(
    const float* __restrict__ hidden, const float* __restrict__ W1,
    const float* __restrict__ b1, float* __restrict__ h1)
{
    __shared__ float hs[4][HID_];
    const int t = threadIdx.x;
    const int d = blockIdx.x * 256 + t;
    const int b0 = blockIdx.y * 4;

    for (int i = t; i < 4 * HID_; i += 256)
        hs[i >> 10][i & 1023] = hidden[(size_t)(b0 + (i >> 10)) * HID_ + (i & 1023)];
    __syncthreads();

    float acc[4] = {};
    for (int h = 0; h < HID_; ++h) {
        const float w = W1[(size_t)h * HID_ + d];
#pragma unroll
        for (int i = 0; i < 4; ++i) acc[i] += hs[i][h] * w;
    }
    const float bias = b1[d];
#pragma unroll
    for (int i = 0; i < 4; ++i)
        h1[(size_t)(b0 + i) * HID_ + d] = acc[i] + bias;
}

// ---------------------------------------------------------------------------
// K0a: pack A = W1s^T (d x c, 1024x2048) into fp16 K-step chunks.
// Chunk (dt2, ks): 256 d x 32 c, layout [cg(4)][dd(256)][c8(8)] = 8192 halfs.
// Global order: [dt2(4)][ks(64)][chunk 8192] — linear idx == dest idx.
// ---------------------------------------------------------------------------
__global__ __launch_bounds__(256) void k0a_packA(
    const float* __restrict__ W1, __half* __restrict__ Ah)
{
    const size_t idx = (size_t)blockIdx.x * 256 + threadIdx.x;  // < 2,097,152
    const int c8 = idx & 7;
    const int dd = (idx >> 3) & 255;
    const int cg = (idx >> 11) & 3;
    const int ks = (idx >> 13) & 63;
    const int dt2 = idx >> 19;
    const int d = dt2 * 256 + dd;
    const int c = ks * 32 + cg * 8 + c8;
    Ah[idx] = __float2half(W1[(size_t)(HID_ + c) * HID_ + d]);
}

// ---------------------------------------------------------------------------
// K0b: pack B = spT (c x j) into fp16 K-step chunks — LDS-free.
// Chunk (jt2, ks): 32 c x 256 j, layout [cg(4)][jj(256)][c8(8)] = 8192 halfs.
// Global order: [jt2(196)][ks(64)][chunk 8192]. One block per chunk.
// ---------------------------------------------------------------------------
__global__ __launch_bounds__(256) void k0b_packB(
    const float* __restrict__ spatial, __half* __restrict__ Bh)
{
    const int jt2 = blockIdx.x;           // 0..195
    const int ks  = blockIdx.y;           // 0..63
    const int jj  = threadIdx.x;          // 0..255

    const int j = jt2 * 256 + jj;
    const int b = j / N_;
    const int n = j - b * N_;
    const float* spj = spatial + (size_t)b * SPB_ + n;
    __half* outb = Bh + (((size_t)jt2 * 64 + ks) * 4) * 2048 + jj * 8;

#pragma unroll
    for (int cg = 0; cg < 4; ++cg) {
        const float* src = spj + (size_t)(ks * 32 + cg * 8) * N_;
        f16x8 v;
#pragma unroll
        for (int c8 = 0; c8 < 8; ++c8)
            v[c8] = (_Float16)src[(size_t)c8 * N_];
        *(f16x8*)(outb + (size_t)cg * 2048) = v;
    }
}

// ---------------------------------------------------------------------------
// K2 (pipelined MFMA): 256x256 tile, 8 waves (2Mx4N), per-wave 128x64.
// BK=32, FULL K=2048 per block (64 K-steps) — tanh epilogue needs the
// complete c-reduction (split-K broke it in R7). 4-slot LDS ring (128 KB),
// stage-ahead-2 via global_load_lds, counted vmcnt(8) (never 0 in loop),
// ONE s_barrier per K-step, s_setprio around the MFMA cluster.
// Hazard: slot S is rewritten only >=2 barriers after its last read. Safe.
// Fused epilogue: ps[dt2*NJ + j] = sum_{d in 256-range} tanh(C+h1)*w2.
// ---------------------------------------------------------------------------
__global__ __launch_bounds__(512, 2) void k2_pipe(
    const __half* __restrict__ Ah, const __half* __restrict__ Bh,
    const float* __restrict__ W2, const float* __restrict__ h1,
    float* __restrict__ ps)
{
    extern __shared__ __align__(16) short ldsb[];   // 4 * 16384 halfs = 128 KB

    const int tid = threadIdx.x;
    const int l  = tid & 63;
    const int w  = tid >> 6;            // wave 0..7
    const int wm = w >> 2;              // 0..1  (d half: 128 rows)
    const int wn = w & 3;               // 0..3  (j quarter: 64 cols)
    const int cg = l >> 4;              // 0..3
    const int rr = l & 15;

    // bijective XCD-chunked swizzle: 784 = 8 * 98; dt2 fastest in chunk.
    const int orig = blockIdx.x;
    const int wgid = (orig & 7) * 98 + (orig >> 3);
    const int jt2 = wgid >> 2;          // 0..195
    const int dt2 = wgid & 3;           // 0..3

    const __half* apack = Ah + ((size_t)dt2 * 64) * 8192;
    const __half* bpack = Bh + ((size_t)jt2 * 64) * 8192;

    f32x4 acc[8][4] = {};

#define STAGE(KT, SLOT) do {                                                    \
        const __half* as_ = apack + (size_t)(KT) * 8192;                        \
        const __half* bs_ = bpack + (size_t)(KT) * 8192;                        \
        short* ad_ = ldsb + (SLOT) * 16384 + w * 1024;                          \
        short* bd_ = ldsb + (SLOT) * 16384 + 8192 + w * 1024;                   \
        __builtin_amdgcn_global_load_lds(GLOBAL_AS(as_ + w * 1024 + l * 8),     \
                                         LDS_AS(ad_), 16, 0, 0);                \
        __builtin_amdgcn_global_load_lds(GLOBAL_AS(as_ + w * 1024 + 512 + l * 8),\
                                         LDS_AS(ad_ + 512), 16, 0, 0);          \
        __builtin_amdgcn_global_load_lds(GLOBAL_AS(bs_ + w * 1024 + l * 8),     \
                                         LDS_AS(bd_), 16, 0, 0);                \
        __builtin_amdgcn_global_load_lds(GLOBAL_AS(bs_ + w * 1024 + 512 + l * 8),\
                                         LDS_AS(bd_ + 512), 16, 0, 0);          \
    } while (0)

#define COMPUTE(SLOT) do {                                                      \
        const short* ab_ = ldsb + (SLOT) * 16384;                               \
        const short* bb_ = ab_ + 8192;                                          \
        f16x8 bf[4], af[8];                                                     \
        _Pragma("unroll")                                                       \
        for (int ni = 0; ni < 4; ++ni)                                          \
            bf[ni] = *(const f16x8*)&bb_[(cg * 256 + wn * 64 + ni * 16 + rr) * 8];\
        _Pragma("unroll")                                                       \
        for (int mi = 0; mi < 8; ++mi)                                          \
            af[mi] = *(const f16x8*)&ab_[(cg * 256 + wm * 128 + mi * 16 + rr) * 8];\
        __builtin_amdgcn_s_setprio(1);                                          \
        _Pragma("unroll")                                                       \
        for (int mi = 0; mi < 8; ++mi)                                          \
            _Pragma("unroll")                                                   \
            for (int ni = 0; ni < 4; ++ni)                                      \
                acc[mi][ni] = __builtin_amdgcn_mfma_f32_16x16x32_f16(           \
                    af[mi], bf[ni], acc[mi][ni], 0, 0, 0);                      \
        __builtin_amdgcn_s_setprio(0);                                          \
    } while (0)

#define STEP(KS, SSLOT, CSLOT, VMC) do {                                        \
        STAGE(KS, SSLOT);                                                       \
        asm volatile("s_waitcnt vmcnt(" #VMC ")" ::: "memory");                 \
        __builtin_amdgcn_s_barrier();                                           \
        __builtin_amdgcn_sched_barrier(0);                                      \
        COMPUTE(CSLOT);                                                         \
    } while (0)

    STAGE(0, 0);
    STAGE(1, 1);
#pragma unroll 1
    for (int kt = 0; kt < 60; kt += 4) {
        STEP(kt + 2, 2, 0, 8);
        STEP(kt + 3, 3, 1, 8);
        STEP(kt + 4, 0, 2, 8);
        STEP(kt + 5, 1, 3, 8);
    }
    // tail: computes 60..63; stages 62,63
    STEP(62, 2, 0, 8);
    STEP(63, 3, 1, 8);
    asm volatile("s_waitcnt vmcnt(4)" ::: "memory");
    __builtin_amdgcn_s_barrier();
    __builtin_amdgcn_sched_barrier(0);
    COMPUTE(2);
    asm volatile("s_waitcnt vmcnt(0)" ::: "memory");
    __builtin_amdgcn_s_barrier();
    __builtin_amdgcn_sched_barrier(0);
    COMPUTE(3);

#undef STAGE
#undef COMPUTE
#undef STEP

    // Epilogue: partial[j] = sum_{d in this block's 256} tanh(acc + h1) * w2
    const int dbase = dt2 * 256 + wm * 128;
    float w2v[8][4];
#pragma unroll
    for (int mi = 0; mi < 8; ++mi)
#pragma unroll
        for (int q = 0; q < 4; ++q)
            w2v[mi][q] = W2[dbase + mi * 16 + cg * 4 + q];

    float partial[4];
#pragma unroll
    for (int ni = 0; ni < 4; ++ni) {
        const int j = jt2 * 256 + wn * 64 + ni * 16 + rr;
        const int bj = j / N_;
        const float* h1p = h1 + (size_t)bj * HID_ + dbase;
        float s = 0.f;
#pragma unroll
        for (int mi = 0; mi < 8; ++mi)
#pragma unroll
            for (int q = 0; q < 4; ++q)
                s += fast_tanh(acc[mi][ni][q] + h1p[mi * 16 + cg * 4 + q]) * w2v[mi][q];
        partial[ni] = s;
    }

    float* red = (float*)ldsb;
    __syncthreads();                 // all waves done with slot-0 LDS reads
    if (tid < 256) red[tid] = 0.f;
    __syncthreads();
#pragma unroll
    for (int ni = 0; ni < 4; ++ni)
        atomicAdd(&red[wn * 64 + ni * 16 + rr], partial[ni]);
    __syncthreads();
    if (tid < 256)
        ps[(size_t)dt2 * NJ_ + (size_t)jt2 * 256 + tid] = red[tid];
}

// ---------------------------------------------------------------------------
// K2 fallback (fp32 vector path) if workspace is too small for packing.
// ---------------------------------------------------------------------------
__global__ __launch_bounds__(256) void k2_fb(
    const float* __restrict__ spatial, const float* __restrict__ W1,
    const float* __restrict__ W2, const float* __restrict__ h1,
    float* __restrict__ ps)
{
    __shared__ float As[32][64];
    __shared__ float Bs[32][64];
    const int t = threadIdx.x;
    const int d0 = blockIdx.x * 64;
    const int j0 = blockIdx.y * 64;
    const int ld = t & 63, lk = t >> 6;
    const float* Aptr = W1 + (size_t)(HID_ + lk) * HID_ + (d0 + ld);
    const int j = j0 + ld;
    const int bb = j / N_, nn = j - bb * N_;
    const float* Bptr = spatial + (size_t)bb * SPB_ + (size_t)lk * N_ + nn;
    const int tr = t >> 4, tc = t & 15;
    float acc[4][4] = {};
    for (int c0 = 0; c0 < SP_; c0 += 32) {
#pragma unroll
        for (int i = 0; i < 8; ++i) {
            As[lk + 4 * i][ld] = Aptr[(size_t)(c0 + 4 * i) * HID_];
            Bs[lk + 4 * i][ld] = Bptr[(size_t)(c0 + 4 * i) * N_];
        }
        __syncthreads();
#pragma unroll
        for (int k = 0; k < 32; ++k) {
            float av[4], bv[4];
            *(float4*)av = *(const float4*)&As[k][tr * 4];
            *(float4*)bv = *(const float4*)&Bs[k][tc * 4];
#pragma unroll
            for (int di = 0; di < 4; ++di)
#pragma unroll
                for (int ji = 0; ji < 4; ++ji)
                    acc[di][ji] += av[di] * bv[ji];
        }
        __syncthreads();
    }
    float w2v[4];
#pragma unroll
    for (int di = 0; di < 4; ++di) w2v[di] = W2[d0 + tr * 4 + di];
    float partial[4] = {};
#pragma unroll
    for (int ji = 0; ji < 4; ++ji) {
        const int jg = j0 + tc * 4 + ji;
        const int bj = jg / N_;
        const float* h1row = h1 + (size_t)bj * HID_ + d0 + tr * 4;
#pragma unroll
        for (int di = 0; di < 4; ++di)
            partial[ji] += tanhf(acc[di][ji] + h1row[di]) * w2v[di];
    }
    __shared__ float red[64];
    if (t < 64) red[t] = 0.f;
    __syncthreads();
#pragma unroll
    for (int ji = 0; ji < 4; ++ji)
        atomicAdd(&red[tc * 4 + ji], partial[ji]);
    __syncthreads();
    if (t < 64)
        ps[(size_t)blockIdx.x * NJ_ + j0 + t] = red[t];
}

// ---------------------------------------------------------------------------
// K3: scores[b,n] = sum_slices ps; attn = softmax_n  (b2 shift-invariant)
// ---------------------------------------------------------------------------
__global__ __launch_bounds__(256) void k3_softmax(
    const float* __restrict__ ps, float* __restrict__ attn, int nslices)
{
    const int b = blockIdx.x;
    const int t = threadIdx.x;
    __shared__ float sdata[256];

    float s = -1e30f;
    if (t < N_) {
        s = 0.f;
        for (int dt = 0; dt < nslices; ++dt)
            s += ps[(size_t)dt * NJ_ + b * N_ + t];
    }
    sdata[t] = s;
    __syncthreads();
    for (int off = 128; off > 0; off >>= 1) {
        if (t < off) sdata[t] = fmaxf(sdata[t], sdata[t + off]);
        __syncthreads();
    }
    const float m = sdata[0];
    __syncthreads();
    const float e = (t < N_) ? expf(s - m) : 0.f;
    sdata[t] = e;
    __syncthreads();
    for (int off = 128; off > 0; off >>= 1) {
        if (t < off) sdata[t] += sdata[t + off];
        __syncthreads();
    }
    const float inv = 1.f / sdata[0];
    if (t < N_) attn[(size_t)b * N_ + t] = e * inv;
}

// ---------------------------------------------------------------------------
// K4: context[b,c] = sum_n attn[b,n] * spatial[b, c*196 + n]
// 196 = 49 float4 (row base 784 B, 16B-aligned). One wave per (b,c).
// ---------------------------------------------------------------------------
__global__ __launch_bounds__(256) void k4_context(
    const float* __restrict__ spatial, const float* __restrict__ attn,
    float* __restrict__ ctx)
{
    const int wid = (blockIdx.x * 256 + threadIdx.x) >> 6;
    const int lane = threadIdx.x & 63;
    const int b = wid >> 11;
    const int c = wid & 2047;
    const float* sp = spatial + (size_t)b * SPB_ + (size_t)c * N_;
    const float* at = attn + (size_t)b * N_;

    float sum = 0.f;
    if (lane < 49) {
        const float4 s4 = ((const float4*)sp)[lane];
        const float4 a4 = ((const float4*)at)[lane];
        sum = s4.x * a4.x + s4.y * a4.y + s4.z * a4.z + s4.w * a4.w;
    }
#pragma unroll
    for (int off = 32; off > 0; off >>= 1)
        sum += __shfl_down(sum, off, 64);
    if (lane == 0)
        ctx[(size_t)b * 2048 + c] = sum;
}

// ---------------------------------------------------------------------------
extern "C" void kernel_launch(void* const* d_in, const int* in_sizes, int n_in,
                              void* d_out, int out_size, void* d_ws, size_t ws_size,
                              hipStream_t stream)
{
    const float* hidden  = (const float*)d_in[0];
    const float* spatial = (const float*)d_in[1];
    const float* W1      = (const float*)d_in[2];
    const float* b1      = (const float*)d_in[3];
    const float* W2      = (const float*)d_in[4];
    // b2 unused: softmax shift-invariant.

    float* out_ctx  = (float*)d_out;
    float* out_attn = (float*)d_out + (size_t)B_ * 2048;

    char* ws = (char*)d_ws;
    float* h1 = (float*)ws;                               // 1 MB
    float* psb = (float*)(ws + (1u << 20));               // 4-16 slices (3.2 MB)

    // MFMA-path workspace layout
    const size_t offAh = 8u << 20;                         // 4 MB
    const size_t offBh = 16u << 20;                        // 205 MB
    const size_t szB   = (size_t)196 * 64 * 8192 * 2;      // 205,520,896 B
    const size_t needed = offBh + szB;                     // ~212 MB

    k1_h1<<<dim3(4, 64), 256, 0, stream>>>(hidden, W1, b1, h1);

    if (ws_size >= needed) {
        __half* Ah = (__half*)(ws + offAh);
        __half* Bh = (__half*)(ws + offBh);
        k0a_packA<<<dim3(8192), 256, 0, stream>>>(W1, Ah);
        k0b_packB<<<dim3(196, 64), 256, 0, stream>>>(spatial, Bh);
        (void)hipFuncSetAttribute((const void*)k2_pipe,
                                  hipFuncAttributeMaxDynamicSharedMemorySize,
                                  131072);
        k2_pipe<<<dim3(784), 512, 131072, stream>>>(Ah, Bh, W2, h1, psb);
        k3_softmax<<<dim3(B_), 256, 0, stream>>>(psb, out_attn, 4);
    } else {
        k2_fb<<<dim3(16, 784), 256, 0, stream>>>(spatial, W1, W2, h1, psb);
        k3_softmax<<<dim3(B_), 256, 0, stream>>>(psb, out_attn, 16);
    }
    k4_context<<<dim3((B_ * 2048) / 4), 256, 0, stream>>>(spatial, out_attn, out_ctx);
}